// Round 3
// baseline (223.812 us; speedup 1.0000x reference)
//
#include <hip/hip_runtime.h>
#include <hip/hip_fp16.h>
#include <math.h>

// TriangleAttentionStartingNode: B=1, N=256, C=128, H=4, AC=32, fp32 in/out.
// R6: precision-lite pipeline (see prior notes).
// R7 FAILED: launch_bounds(256,4) forced VGPR=64 -> spill traffic, no gain.
// R8 WIN(+11%): zero-barrier lnproj, wave-private LDS, 64.8->57.4us. But
//   grid 512 = 2 blocks/CU -> occupancy capped at 20%; still all-idle
//   (VALU 15%, MFMA 5%, HBM 18%) => latency-bound with too few waves.
// R9: 2-tensors-per-wave split. Wave pair shares a 32-row set: wave A
//   does LN+nb+{q,k}, wave B does LN(redundant)+{v,g}. Grid 1024 =
//   4 blocks/CU = 16 waves/CU (2x), per-wave chain halved, weight L2
//   traffic unchanged. act re-read by wave B hits L1 (same CU).
//   Pre-committed: if occupancy ~45% but dur >=50us, occupancy is NOT
//   the limiter -> R10 = coalesced act staging + fuse attn+out.

#define NRES 256
#define CCH  128
#define NROWS (NRES * NRES)          // 65536
#define FACTOR 0.17677669529663687f  // 1/sqrt(32)

typedef __attribute__((ext_vector_type(8))) __bf16 bf16x8;
typedef __attribute__((ext_vector_type(4))) float f32x4;

__device__ __forceinline__ f32x4 mfma16(bf16x8 a, bf16x8 b, f32x4 c) {
    return __builtin_amdgcn_mfma_f32_16x16x32_bf16(a, b, c, 0, 0, 0);
}

union PK4 { __bf16 b[4]; uint2 u2; };
union PK2 { __bf16 b[2]; unsigned int u; };

__device__ __forceinline__ void hilo(float x, __bf16& h, __bf16& l) {
    h = (__bf16)x;
    l = (__bf16)(x - (float)h);
}

// ---------------- weight prep: pack into B-frag layout ----------------
// hi planes used by lnproj (single-MFMA GEMMs); lo planes only read for wo.
__global__ __launch_bounds__(256) void prep_kernel(
    const float* __restrict__ wq, const float* __restrict__ wk,
    const float* __restrict__ wv, const float* __restrict__ wg,
    const float* __restrict__ wo,
    __bf16* __restrict__ wph, __bf16* __restrict__ wpl)
{
    const int gid = blockIdx.x * 256 + threadIdx.x;   // 0..10239
    const int wid = gid >> 11;
    const int rem = gid & 2047;
    const int nstrip = rem >> 8;
    const int kf = (rem >> 6) & 3;
    const int lane = rem & 63;
    const int l15 = lane & 15, quad = lane >> 4;
    const float* W = (wid == 0) ? wq : (wid == 1) ? wk :
                     (wid == 2) ? wv : (wid == 3) ? wg : wo;
    const float scale = (wid == 0) ? FACTOR : 1.0f;
    bf16x8 hb, lb;
    #pragma unroll
    for (int e = 0; e < 8; ++e) {
        int k = kf * 32 + quad * 8 + e;
        int n = nstrip * 16 + l15;
        float v = W[k * CCH + n] * scale;
        __bf16 h, l; hilo(v, h, l);
        hb[e] = h; lb[e] = l;
    }
    *(bf16x8*)&wph[(size_t)gid * 8] = hb;
    *(bf16x8*)&wpl[(size_t)gid * 8] = lb;
}

// ---------------- fused LN + nb + projection (zero-barrier) ----------------
// R9: wave pair shares 32 rows; each wave computes LN + 2 tensors.
__global__ __launch_bounds__(256) void lnproj_kernel(
    const float* __restrict__ act, const float* __restrict__ ln_g,
    const float* __restrict__ ln_b, const float* __restrict__ w2d,
    const __bf16* __restrict__ wph, const float* __restrict__ bg,
    __bf16* __restrict__ qb, __bf16* __restrict__ kb,
    __bf16* __restrict__ vb, __half* __restrict__ gfh,
    float* __restrict__ nbP)
{
    __shared__ __align__(16) char smem[34816];       // 4 x 8704B wave-private
    const int t = threadIdx.x, w = t >> 6, lane = t & 63;
    const int l15 = lane & 15, quad = lane >> 4;
    __bf16* const aH = (__bf16*)(smem + w * 8704);   // [32][136] bf16
    const int r0w = blockIdx.x * 64 + (w >> 1) * 32; // wave pair -> row set
    const int tpair = (w & 1) * 2;                   // tensors {tpair,tpair+1}

    // ---- Phase A: LayerNorm (+ nb on even waves), 2 lanes/row ----
    {
        const int row = lane >> 1, half = lane & 1;
        const int grow = r0w + row;
        const float* __restrict__ xp = act + (size_t)grow * CCH + half * 64;
        float4 x4[16];
        #pragma unroll
        for (int c = 0; c < 16; ++c) x4[c] = *(const float4*)(xp + c * 4);
        float s = 0.f, sq = 0.f;
        #pragma unroll
        for (int c = 0; c < 16; ++c) {
            s  += (x4[c].x + x4[c].y) + (x4[c].z + x4[c].w);
            sq += x4[c].x * x4[c].x + x4[c].y * x4[c].y +
                  x4[c].z * x4[c].z + x4[c].w * x4[c].w;
        }
        s  += __shfl_xor(s, 1, 64);
        sq += __shfl_xor(sq, 1, 64);
        float mu  = s * (1.0f / CCH);
        float var = fmaf(sq, 1.0f / CCH, -mu * mu);
        float rs  = rsqrtf(var + 1e-5f);
        if ((w & 1) == 0) {
            // even wave: LN pack + nb
            float nb[4] = {0.f, 0.f, 0.f, 0.f};
            const float4* __restrict__ w2d4 = (const float4*)w2d;
            #pragma unroll
            for (int c2 = 0; c2 < 8; ++c2) {
                bf16x8 pk;
                #pragma unroll
                for (int cc = 0; cc < 2; ++cc) {
                    const int c = c2 * 2 + cc;
                    float4 g4 = *(const float4*)&ln_g[half * 64 + c * 4];
                    float4 b4 = *(const float4*)&ln_b[half * 64 + c * 4];
                    float* xv = (float*)&x4[c];
                    float* gv = (float*)&g4;
                    float* bv = (float*)&b4;
                    #pragma unroll
                    for (int e = 0; e < 4; ++e) {
                        float av = fmaf((xv[e] - mu) * rs, gv[e], bv[e]);
                        pk[cc * 4 + e] = (__bf16)av;
                        float4 wv = w2d4[half * 64 + c * 4 + e];
                        nb[0] = fmaf(av, wv.x, nb[0]);
                        nb[1] = fmaf(av, wv.y, nb[1]);
                        nb[2] = fmaf(av, wv.z, nb[2]);
                        nb[3] = fmaf(av, wv.w, nb[3]);
                    }
                }
                *(bf16x8*)&aH[row * 136 + half * 64 + c2 * 8] = pk;
            }
            #pragma unroll
            for (int hh = 0; hh < 4; ++hh)
                nb[hh] += __shfl_xor(nb[hh], 1, 64);
            if (half == 0) {
                const int i = grow >> 8, j = grow & 255;
                #pragma unroll
                for (int hh = 0; hh < 4; ++hh) {
                    size_t f = ((size_t)hh << 14) + ((size_t)(i >> 4) << 10) +
                               ((size_t)(j >> 4) << 6) + ((size_t)((j >> 2) & 3) << 4) +
                               (i & 15);
                    nbP[f * 4 + (j & 3)] = nb[hh];
                }
            }
        } else {
            // odd wave: LN pack only
            #pragma unroll
            for (int c2 = 0; c2 < 8; ++c2) {
                bf16x8 pk;
                #pragma unroll
                for (int cc = 0; cc < 2; ++cc) {
                    const int c = c2 * 2 + cc;
                    float4 g4 = *(const float4*)&ln_g[half * 64 + c * 4];
                    float4 b4 = *(const float4*)&ln_b[half * 64 + c * 4];
                    float* xv = (float*)&x4[c];
                    float* gv = (float*)&g4;
                    float* bv = (float*)&b4;
                    #pragma unroll
                    for (int e = 0; e < 4; ++e) {
                        float av = fmaf((xv[e] - mu) * rs, gv[e], bv[e]);
                        pk[cc * 4 + e] = (__bf16)av;
                    }
                }
                *(bf16x8*)&aH[row * 136 + half * 64 + c2 * 8] = pk;
            }
        }
    }

    // ---- A-frags to regs (same-wave LDS dep; compiler inserts lgkmcnt).
    // aH becomes dead afterwards -> recycled as epilogue staging plane.
    bf16x8 A0[4], A1[4];
    #pragma unroll
    for (int kf = 0; kf < 4; ++kf) {
        const int ao = l15 * 136 + kf * 32 + quad * 8;
        A0[kf] = *(const bf16x8*)&aH[ao];
        A1[kf] = *(const bf16x8*)&aH[ao + 16 * 136];
    }

    // ---- Phase B: this wave's 2 tensors for its 32 rows ----
    #pragma unroll 1
    for (int ti = 0; ti < 2; ++ti) {
        const int tn = tpair + ti;
        const __bf16* __restrict__ Bh = wph + (size_t)tn * 16384;
        f32x4 acc0[8], acc1[8];
        #pragma unroll
        for (int n = 0; n < 8; ++n) {
            acc0[n] = (f32x4){0.f, 0.f, 0.f, 0.f};
            acc1[n] = (f32x4){0.f, 0.f, 0.f, 0.f};
        }
        #pragma unroll
        for (int kf = 0; kf < 4; ++kf)
            #pragma unroll
            for (int n = 0; n < 8; ++n) {
                bf16x8 bh = *(const bf16x8*)&Bh[(size_t)((n * 4 + kf) * 64 + lane) * 8];
                acc0[n] = mfma16(A0[kf], bh, acc0[n]);
                acc1[n] = mfma16(A1[kf], bh, acc1[n]);
            }

        if (tn == 3) {
            __half* const sth = (__half*)aH;     // recycled staging [16][136]
            #pragma unroll 1
            for (int sp = 0; sp < 2; ++sp) {
                f32x4* accp = sp ? acc1 : acc0;
                #pragma unroll
                for (int n = 0; n < 8; ++n)
                    #pragma unroll
                    for (int r = 0; r < 4; ++r) {
                        float v = accp[n][r] + bg[n * 16 + l15];
                        sth[(quad * 4 + r) * 136 + n * 16 + l15] =
                            (__half)(1.0f / (1.0f + __expf(-v)));
                    }
                #pragma unroll
                for (int i = 0; i < 4; ++i) {
                    int row = i * 4 + (lane >> 4);
                    int c8 = lane & 15;
                    uint4 hv = *(const uint4*)&sth[row * 136 + c8 * 8];
                    *(uint4*)&gfh[(size_t)(r0w + sp * 16 + row) * CCH + c8 * 8] = hv;
                }
            }
        } else {
            __bf16* const sth = (__bf16*)aH;     // recycled staging [16][136]
            __bf16* const oh = (tn == 0) ? qb : (tn == 1) ? kb : vb;
            #pragma unroll 1
            for (int sp = 0; sp < 2; ++sp) {
                f32x4* accp = sp ? acc1 : acc0;
                #pragma unroll
                for (int n = 0; n < 8; ++n)
                    #pragma unroll
                    for (int r = 0; r < 4; ++r)
                        sth[(quad * 4 + r) * 136 + n * 16 + l15] = (__bf16)accp[n][r];
                #pragma unroll
                for (int i = 0; i < 4; ++i) {
                    int row = i * 4 + (lane >> 4);
                    int c8 = lane & 15;
                    uint4 hv = *(const uint4*)&sth[row * 136 + c8 * 8];
                    *(uint4*)&oh[(size_t)(r0w + sp * 16 + row) * CCH + c8 * 8] = hv;
                }
            }
        }
    }
}

// ---------------- attention (single-bf16 S^T path) ----------------
__global__ __launch_bounds__(256) void attn_kernel(
    const __bf16* __restrict__ qb, const __bf16* __restrict__ kb,
    const __bf16* __restrict__ vb, const __half* __restrict__ gfh,
    const float* __restrict__ mask, const float* __restrict__ nbP,
    __bf16* __restrict__ gth, __bf16* __restrict__ gtl)
{
    __shared__ __align__(16) char smem[23040];
    __bf16* const vth = (__bf16*)smem;               // [32][264] = 16896B
    __bf16* const pbb = (__bf16*)(smem + 16896);     // [4][16][40] = 5120B
    float*  const biasrow = (float*)(smem + 22016);  // [256]
    const int t = threadIdx.x, w = t >> 6, lane = t & 63;
    const int l15 = lane & 15, quad = lane >> 4;
    const int mrow = blockIdx.x >> 2, h = blockIdx.x & 3;
    const size_t rbase = (size_t)mrow * NRES;
    const int ch0 = h * 32;

    biasrow[t] = 1e9f * (mask[mrow * NRES + t] - 1.0f);

    // V^T staging (single plane)
    #pragma unroll
    for (int it = 0; it < 4; ++it) {
        int f = t + it * 256;
        int j = f >> 2, cg = f & 3;
        bf16x8 hv = *(const bf16x8*)&vb[(rbase + j) * CCH + ch0 + cg * 8];
        #pragma unroll
        for (int e = 0; e < 8; ++e)
            vth[(cg * 8 + e) * 264 + j] = hv[e];
    }
    __syncthreads();

    const int i0 = w * 64;
    bf16x8 Qh[4];
    #pragma unroll
    for (int s = 0; s < 4; ++s)
        Qh[s] = *(const bf16x8*)&qb[(rbase + i0 + s * 16 + l15) * CCH + ch0 + quad * 8];

    f32x4 O[4][2];
    float ls[4] = {0.f, 0.f, 0.f, 0.f};
    #pragma unroll
    for (int s = 0; s < 4; ++s) {
        O[s][0] = (f32x4){0.f, 0.f, 0.f, 0.f};
        O[s][1] = (f32x4){0.f, 0.f, 0.f, 0.f};
    }
    __bf16* const ph = pbb + w * 640;

    for (int jb = 0; jb < NRES; jb += 32) {
        bf16x8 Kh[2];
        #pragma unroll
        for (int js = 0; js < 2; ++js)
            Kh[js] = *(const bf16x8*)&kb[(rbase + jb + js * 16 + l15) * CCH + ch0 + quad * 8];
        bf16x8 Vh2[2];
        #pragma unroll
        for (int c = 0; c < 2; ++c)
            Vh2[c] = *(const bf16x8*)&vth[(c * 16 + l15) * 264 + jb + quad * 8];
        #pragma unroll
        for (int s = 0; s < 4; ++s) {
            #pragma unroll
            for (int js = 0; js < 2; ++js) {
                f32x4 S = (f32x4){0.f, 0.f, 0.f, 0.f};
                S = mfma16(Kh[js], Qh[s], S);
                size_t f4 = (((size_t)(h * 16 + w * 4 + s) * 16 +
                              (jb >> 4) + js) << 6) + quad * 16 + l15;
                float4 nb4 = *(const float4*)&nbP[f4 * 4];
                float4 mb4 = *(const float4*)&biasrow[jb + js * 16 + quad * 4];
                float p0 = __expf(S[0] + nb4.x + mb4.x - 4.0f);
                float p1 = __expf(S[1] + nb4.y + mb4.y - 4.0f);
                float p2 = __expf(S[2] + nb4.z + mb4.z - 4.0f);
                float p3 = __expf(S[3] + nb4.w + mb4.w - 4.0f);
                ls[s] += (p0 + p1) + (p2 + p3);
                PK4 hh;
                hh.b[0] = (__bf16)p0; hh.b[1] = (__bf16)p1;
                hh.b[2] = (__bf16)p2; hh.b[3] = (__bf16)p3;
                *(uint2*)&ph[l15 * 40 + js * 16 + quad * 4] = hh.u2;
            }
            bf16x8 Ph = *(const bf16x8*)&ph[l15 * 40 + quad * 8];
            #pragma unroll
            for (int c = 0; c < 2; ++c)
                O[s][c] = mfma16(Vh2[c], Ph, O[s][c]);
        }
    }

    #pragma unroll
    for (int s = 0; s < 4; ++s) {
        ls[s] += __shfl_xor(ls[s], 16, 64);
        ls[s] += __shfl_xor(ls[s], 32, 64);
    }

    // epilogue: gate (fp16 g), hi/lo output via two-pass per-wave staging
    float ov[4][2][4];
    #pragma unroll
    for (int s = 0; s < 4; ++s) {
        float inv = 1.0f / ls[s];
        #pragma unroll
        for (int c = 0; c < 2; ++c) {
            size_t gi = (rbase + i0 + s * 16 + l15) * CCH + ch0 + c * 16 + quad * 4;
            uint2 gu = *(const uint2*)&gfh[gi];
            const __half* gh = (const __half*)&gu;
            #pragma unroll
            for (int r = 0; r < 4; ++r)
                ov[s][c][r] = O[s][c][r] * inv * (float)gh[r];
        }
    }
    __syncthreads();   // vth/pb dead for all waves
    __bf16* const stp = (__bf16*)(smem + w * 5120);   // [64][40]
    #pragma unroll
    for (int s = 0; s < 4; ++s)
        #pragma unroll
        for (int c = 0; c < 2; ++c) {
            PK4 hh;
            #pragma unroll
            for (int r = 0; r < 4; ++r) hh.b[r] = (__bf16)ov[s][c][r];
            *(uint2*)&stp[(s * 16 + l15) * 40 + c * 16 + quad * 4] = hh.u2;
        }
    #pragma unroll
    for (int i = 0; i < 4; ++i) {
        int row = i * 16 + (lane >> 2);
        int c8 = lane & 3;
        uint4 hv = *(const uint4*)&stp[row * 40 + c8 * 8];
        *(uint4*)&gth[(rbase + i0 + row) * CCH + ch0 + c8 * 8] = hv;
    }
    #pragma unroll
    for (int s = 0; s < 4; ++s)
        #pragma unroll
        for (int c = 0; c < 2; ++c) {
            PK4 ll;
            #pragma unroll
            for (int r = 0; r < 4; ++r) {
                __bf16 hv = (__bf16)ov[s][c][r];
                ll.b[r] = (__bf16)(ov[s][c][r] - (float)hv);
            }
            *(uint2*)&stp[(s * 16 + l15) * 40 + c * 16 + quad * 4] = ll.u2;
        }
    #pragma unroll
    for (int i = 0; i < 4; ++i) {
        int row = i * 16 + (lane >> 2);
        int c8 = lane & 3;
        uint4 lv = *(const uint4*)&stp[row * 40 + c8 * 8];
        *(uint4*)&gtl[(rbase + i0 + row) * CCH + ch0 + c8 * 8] = lv;
    }
}

// ---------------- output GEMM (split MFMA): gated @ wo + bo -> fp32 --------
__global__ __launch_bounds__(256) void out_kernel(
    const __bf16* __restrict__ gth, const __bf16* __restrict__ gtl,
    const __bf16* __restrict__ wph, const __bf16* __restrict__ wpl,
    const float* __restrict__ bo, float* __restrict__ out)
{
    __shared__ __align__(16) float eps[4][16 * 132];
    const int t = threadIdx.x, w = t >> 6, lane = t & 63;
    const int l15 = lane & 15, quad = lane >> 4;
    const int r0 = blockIdx.x * 64 + w * 16;
    const __bf16* __restrict__ Bh = wph + (size_t)4 * 16384;
    const __bf16* __restrict__ Bl = wpl + (size_t)4 * 16384;

    f32x4 acc[8];
    #pragma unroll
    for (int n = 0; n < 8; ++n) acc[n] = (f32x4){0.f, 0.f, 0.f, 0.f};

    #pragma unroll
    for (int kf = 0; kf < 4; ++kf) {
        size_t idx = (size_t)(r0 + l15) * CCH + kf * 32 + quad * 8;
        bf16x8 Ahf = *(const bf16x8*)&gth[idx];
        bf16x8 Alf = *(const bf16x8*)&gtl[idx];
        #pragma unroll
        for (int n = 0; n < 8; ++n) {
            size_t boff = (size_t)((n * 4 + kf) * 64 + lane) * 8;
            bf16x8 bh = *(const bf16x8*)&Bh[boff];
            bf16x8 bl = *(const bf16x8*)&Bl[boff];
            acc[n] = mfma16(Ahf, bh, acc[n]);
            acc[n] = mfma16(Ahf, bl, acc[n]);
            acc[n] = mfma16(Alf, bh, acc[n]);
        }
    }

    #pragma unroll
    for (int n = 0; n < 8; ++n)
        #pragma unroll
        for (int r = 0; r < 4; ++r)
            eps[w][(quad * 4 + r) * 132 + n * 16 + l15] = acc[n][r];
    const int erow = lane >> 2;
    const int ecg0 = lane & 3;
    #pragma unroll
    for (int it = 0; it < 8; ++it) {
        int cg = ecg0 + it * 4;
        float4 v4 = *(const float4*)&eps[w][erow * 132 + cg * 4];
        float4 b4 = *(const float4*)&bo[cg * 4];
        v4.x += b4.x; v4.y += b4.y; v4.z += b4.z; v4.w += b4.w;
        *(float4*)&out[(size_t)(r0 + erow) * CCH + cg * 4] = v4;
    }
}

extern "C" void kernel_launch(void* const* d_in, const int* in_sizes, int n_in,
                              void* d_out, int out_size, void* d_ws, size_t ws_size,
                              hipStream_t stream)
{
    const float* act  = (const float*)d_in[0];
    const float* mask = (const float*)d_in[1];
    const float* ln_g = (const float*)d_in[2];
    const float* ln_b = (const float*)d_in[3];
    const float* wq   = (const float*)d_in[4];
    const float* wk   = (const float*)d_in[5];
    const float* wv   = (const float*)d_in[6];
    const float* w2d  = (const float*)d_in[7];
    const float* wg   = (const float*)d_in[8];
    const float* bg   = (const float*)d_in[9];
    const float* wo   = (const float*)d_in[10];
    const float* bo   = (const float*)d_in[11];
    float* out = (float*)d_out;

    const size_t SZ = (size_t)NROWS * CCH;   // 8388608 elems
    __bf16* bws = (__bf16*)d_ws;
    __bf16* qb  = bws;
    __bf16* kb  = bws + SZ;
    __bf16* vb  = bws + 2 * SZ;
    __bf16* gth = bws + 3 * SZ;
    __bf16* gtl = bws + 4 * SZ;
    __half* gfh = (__half*)(bws + 5 * SZ);     // SZ halves
    float* nbP = (float*)(bws + 6 * SZ);       // 4*NROWS floats
    __bf16* wph = (__bf16*)(nbP + 4 * NROWS);  // 5*16384 bf16
    __bf16* wpl = wph + 5 * 16384;

    prep_kernel<<<40, 256, 0, stream>>>(wq, wk, wv, wg, wo, wph, wpl);
    lnproj_kernel<<<1024, 256, 0, stream>>>(
        act, ln_g, ln_b, w2d, wph, bg, qb, kb, vb, gfh, nbP);
    attn_kernel<<<NRES * 4, 256, 0, stream>>>(
        qb, kb, vb, gfh, mask, nbP, gth, gtl);
    out_kernel<<<1024, 256, 0, stream>>>(gth, gtl, wph, wpl, bo, out);
}

// Round 4
// 193.823 us; speedup vs baseline: 1.1547x; 1.1547x over previous
//
#include <hip/hip_runtime.h>
#include <hip/hip_fp16.h>
#include <math.h>

// TriangleAttentionStartingNode: B=1, N=256, C=128, H=4, AC=32, fp32 in/out.
// R6: precision-lite pipeline (bf16 q/k/v/P, fp16 g, hi/lo split only on
//     the out-GEMM). absmax 6.1e-5.
// R7 FAILED: launch_bounds(256,4) -> VGPR 64 -> spills. Occupancy not lever.
// R8 WIN(+11%): zero-barrier lnproj (wave-private LDS planes). 64.8->57.4us.
// R9 FAILED: 2-tensor/wave split -> 78us. Four variants pin lnproj at ~60us
//     with ALL pipes <20% -> local minimum; per-kernel ramp ~50us regardless
//     of structure. 250MB of inter-kernel intermediates is the real disease.
// R10: FULL FUSION. nb (global dep) -> tiny nb_kernel. mega_kernel: per
//     pair-row m (256 blocks, 512 thr, 148.5KB LDS): LN+proj (q,g->regs,
//     k,v->LDS; wave planes concatenate to K[256][136]) -> barrier -> 4-head
//     attention from LDS (inner math identical to verified attn kernel) ->
//     barrier -> hi/lo restage -> 3-term out-GEMM -> store. Intermediates
//     never touch HBM. h-loops fully unrolled (no runtime-indexed reg arrays).

#define NRES 256
#define CCH  128
#define NROWS (NRES * NRES)          // 65536
#define FACTOR 0.17677669529663687f  // 1/sqrt(32)

typedef __attribute__((ext_vector_type(8))) __bf16 bf16x8;
typedef __attribute__((ext_vector_type(4))) float f32x4;

__device__ __forceinline__ f32x4 mfma16(bf16x8 a, bf16x8 b, f32x4 c) {
    return __builtin_amdgcn_mfma_f32_16x16x32_bf16(a, b, c, 0, 0, 0);
}

union PK4 { __bf16 b[4]; uint2 u2; };

__device__ __forceinline__ void hilo(float x, __bf16& h, __bf16& l) {
    h = (__bf16)x;
    l = (__bf16)(x - (float)h);
}

// ---------------- weight prep: pack into B-frag layout ----------------
__global__ __launch_bounds__(256) void prep_kernel(
    const float* __restrict__ wq, const float* __restrict__ wk,
    const float* __restrict__ wv, const float* __restrict__ wg,
    const float* __restrict__ wo,
    __bf16* __restrict__ wph, __bf16* __restrict__ wpl)
{
    const int gid = blockIdx.x * 256 + threadIdx.x;   // 0..10239
    const int wid = gid >> 11;
    const int rem = gid & 2047;
    const int nstrip = rem >> 8;
    const int kf = (rem >> 6) & 3;
    const int lane = rem & 63;
    const int l15 = lane & 15, quad = lane >> 4;
    const float* W = (wid == 0) ? wq : (wid == 1) ? wk :
                     (wid == 2) ? wv : (wid == 3) ? wg : wo;
    const float scale = (wid == 0) ? FACTOR : 1.0f;
    bf16x8 hb, lb;
    #pragma unroll
    for (int e = 0; e < 8; ++e) {
        int k = kf * 32 + quad * 8 + e;
        int n = nstrip * 16 + l15;
        float v = W[k * CCH + n] * scale;
        __bf16 h, l; hilo(v, h, l);
        hb[e] = h; lb[e] = l;
    }
    *(bf16x8*)&wph[(size_t)gid * 8] = hb;
    *(bf16x8*)&wpl[(size_t)gid * 8] = lb;
}

// ---------------- nb kernel: LN + w2d dot -> nbP (global dep) -------------
__global__ __launch_bounds__(256) void nb_kernel(
    const float* __restrict__ act, const float* __restrict__ ln_g,
    const float* __restrict__ ln_b, const float* __restrict__ w2d,
    float* __restrict__ nbP)
{
    const int t = threadIdx.x, w = t >> 6, lane = t & 63;
    const int r0w = blockIdx.x * 128 + w * 32;
    const int row = lane >> 1, half = lane & 1;
    const int grow = r0w + row;
    const float* __restrict__ xp = act + (size_t)grow * CCH + half * 64;
    float4 x4[16];
    #pragma unroll
    for (int c = 0; c < 16; ++c) x4[c] = *(const float4*)(xp + c * 4);
    float s = 0.f, sq = 0.f;
    #pragma unroll
    for (int c = 0; c < 16; ++c) {
        s  += (x4[c].x + x4[c].y) + (x4[c].z + x4[c].w);
        sq += x4[c].x * x4[c].x + x4[c].y * x4[c].y +
              x4[c].z * x4[c].z + x4[c].w * x4[c].w;
    }
    s  += __shfl_xor(s, 1, 64);
    sq += __shfl_xor(sq, 1, 64);
    float mu  = s * (1.0f / CCH);
    float var = fmaf(sq, 1.0f / CCH, -mu * mu);
    float rs  = rsqrtf(var + 1e-5f);
    float nb[4] = {0.f, 0.f, 0.f, 0.f};
    const float4* __restrict__ w2d4 = (const float4*)w2d;
    #pragma unroll
    for (int c = 0; c < 16; ++c) {
        float4 g4 = *(const float4*)&ln_g[half * 64 + c * 4];
        float4 b4 = *(const float4*)&ln_b[half * 64 + c * 4];
        float* xv = (float*)&x4[c];
        float* gv = (float*)&g4;
        float* bv = (float*)&b4;
        #pragma unroll
        for (int e = 0; e < 4; ++e) {
            float av = fmaf((xv[e] - mu) * rs, gv[e], bv[e]);
            float4 wv = w2d4[half * 64 + c * 4 + e];
            nb[0] = fmaf(av, wv.x, nb[0]);
            nb[1] = fmaf(av, wv.y, nb[1]);
            nb[2] = fmaf(av, wv.z, nb[2]);
            nb[3] = fmaf(av, wv.w, nb[3]);
        }
    }
    #pragma unroll
    for (int hh = 0; hh < 4; ++hh)
        nb[hh] += __shfl_xor(nb[hh], 1, 64);
    if (half == 0) {
        const int i = grow >> 8, j = grow & 255;
        #pragma unroll
        for (int hh = 0; hh < 4; ++hh) {
            size_t f = ((size_t)hh << 14) + ((size_t)(i >> 4) << 10) +
                       ((size_t)(j >> 4) << 6) + ((size_t)((j >> 2) & 3) << 4) +
                       (i & 15);
            nbP[f * 4 + (j & 3)] = nb[hh];
        }
    }
}

// ---------------- projection helper: 32 rows x 128 out-ch, single bf16 ----
__device__ __forceinline__ void proj32(const bf16x8* A0, const bf16x8* A1,
    const __bf16* __restrict__ Bh, int lane, f32x4* acc0, f32x4* acc1)
{
    #pragma unroll
    for (int n = 0; n < 8; ++n) {
        acc0[n] = (f32x4){0.f, 0.f, 0.f, 0.f};
        acc1[n] = (f32x4){0.f, 0.f, 0.f, 0.f};
    }
    #pragma unroll
    for (int kf = 0; kf < 4; ++kf)
        #pragma unroll
        for (int n = 0; n < 8; ++n) {
            bf16x8 bh = *(const bf16x8*)&Bh[(size_t)((n * 4 + kf) * 64 + lane) * 8];
            acc0[n] = mfma16(A0[kf], bh, acc0[n]);
            acc1[n] = mfma16(A1[kf], bh, acc1[n]);
        }
}

// ---------------- mega kernel: LN+proj + 4-head attn + out GEMM ----------
// One block per pair-row m. 8 waves, wave w owns rows j in [w*32, w*32+32).
// LDS: [0)        K / wave planes: 8 x [32][136] bf16 = 69632 B (K[256][136])
//      [69632)    V^T [128][264] bf16                 = 67584 B
//      [137216)   p-buffers 8 x [16][40] bf16         = 10240 B
//      [147456)   biasrow [256] f32                   =  1024 B   tot 148480
__global__ __launch_bounds__(512) void mega_kernel(
    const float* __restrict__ act, const float* __restrict__ ln_g,
    const float* __restrict__ ln_b, const __bf16* __restrict__ wph,
    const __bf16* __restrict__ wpl, const float* __restrict__ bg,
    const float* __restrict__ mask, const float* __restrict__ nbP,
    const float* __restrict__ bo, float* __restrict__ out)
{
    __shared__ __align__(16) char smem[148480];
    const int t = threadIdx.x, w = t >> 6, lane = t & 63;
    const int l15 = lane & 15, quad = lane >> 4;
    const int m = blockIdx.x;
    __bf16* const Kl = (__bf16*)smem;                        // [256][136]
    __bf16* const aH = (__bf16*)(smem + w * 8704);           // plane w [32][136]
    __bf16* const VT = (__bf16*)(smem + 69632);              // [128][264]
    __bf16* const ph = (__bf16*)(smem + 137216 + w * 1280);  // [16][40]
    float*  const biasrow = (float*)(smem + 147456);         // [256]

    if (t < 256) biasrow[t] = 1e9f * (mask[m * NRES + t] - 1.0f);

    // ---- Phase A: LN of this wave's 32 rows -> aH (2 lanes/row) ----
    {
        const int row = lane >> 1, half = lane & 1;
        const int grow = m * NRES + w * 32 + row;
        const float* __restrict__ xp = act + (size_t)grow * CCH + half * 64;
        float4 x4[16];
        #pragma unroll
        for (int c = 0; c < 16; ++c) x4[c] = *(const float4*)(xp + c * 4);
        float s = 0.f, sq = 0.f;
        #pragma unroll
        for (int c = 0; c < 16; ++c) {
            s  += (x4[c].x + x4[c].y) + (x4[c].z + x4[c].w);
            sq += x4[c].x * x4[c].x + x4[c].y * x4[c].y +
                  x4[c].z * x4[c].z + x4[c].w * x4[c].w;
        }
        s  += __shfl_xor(s, 1, 64);
        sq += __shfl_xor(sq, 1, 64);
        float mu  = s * (1.0f / CCH);
        float var = fmaf(sq, 1.0f / CCH, -mu * mu);
        float rs  = rsqrtf(var + 1e-5f);
        #pragma unroll
        for (int c2 = 0; c2 < 8; ++c2) {
            bf16x8 pk;
            #pragma unroll
            for (int cc = 0; cc < 2; ++cc) {
                const int c = c2 * 2 + cc;
                float4 g4 = *(const float4*)&ln_g[half * 64 + c * 4];
                float4 b4 = *(const float4*)&ln_b[half * 64 + c * 4];
                float* xv = (float*)&x4[c];
                float* gv = (float*)&g4;
                float* bv = (float*)&b4;
                #pragma unroll
                for (int e = 0; e < 4; ++e)
                    pk[cc * 4 + e] = (__bf16)fmaf((xv[e] - mu) * rs, gv[e], bv[e]);
            }
            *(bf16x8*)&aH[row * 136 + half * 64 + c2 * 8] = pk;
        }
    }

    // ---- A-frags to regs (same-wave LDS dep). aH plane then recyclable.
    bf16x8 A0[4], A1[4];
    #pragma unroll
    for (int kf = 0; kf < 4; ++kf) {
        const int ao = l15 * 136 + kf * 32 + quad * 8;
        A0[kf] = *(const bf16x8*)&aH[ao];
        A1[kf] = *(const bf16x8*)&aH[ao + 16 * 136];
    }

    f32x4 acc0[8], acc1[8];
    bf16x8 Qh[4][2];          // [head][s]  B-frag of own q rows
    uint2  greg[4][2][2];     // [head][s][c] 4 fp16 gate vals

    // ---- q: project, restage through own plane, hoist B-frags ----
    proj32(A0, A1, wph, lane, acc0, acc1);
    {
        __bf16* const sth = aH;
        #pragma unroll
        for (int sp = 0; sp < 2; ++sp) {
            f32x4* accp = sp ? acc1 : acc0;
            #pragma unroll
            for (int n = 0; n < 8; ++n)
                #pragma unroll
                for (int r = 0; r < 4; ++r)
                    sth[(quad * 4 + r) * 136 + n * 16 + l15] = (__bf16)accp[n][r];
            #pragma unroll
            for (int h = 0; h < 4; ++h)
                Qh[h][sp] = *(const bf16x8*)&sth[l15 * 136 + h * 32 + quad * 8];
        }
    }

    // ---- g: project + bias + sigmoid (fp16), restage, hoist gate regs ----
    proj32(A0, A1, wph + 3 * 16384, lane, acc0, acc1);
    {
        __half* const sthH = (__half*)aH;
        #pragma unroll
        for (int sp = 0; sp < 2; ++sp) {
            f32x4* accp = sp ? acc1 : acc0;
            #pragma unroll
            for (int n = 0; n < 8; ++n)
                #pragma unroll
                for (int r = 0; r < 4; ++r) {
                    float v = accp[n][r] + bg[n * 16 + l15];
                    sthH[(quad * 4 + r) * 136 + n * 16 + l15] =
                        (__half)(1.0f / (1.0f + __expf(-v)));
                }
            #pragma unroll
            for (int h = 0; h < 4; ++h)
                #pragma unroll
                for (int c = 0; c < 2; ++c)
                    greg[h][sp][c] =
                        *(const uint2*)&sthH[l15 * 136 + h * 32 + c * 16 + quad * 4];
        }
    }

    // ---- k: project, write straight into own plane (= K rows) ----
    proj32(A0, A1, wph + 1 * 16384, lane, acc0, acc1);
    {
        __bf16* const Kp = aH;
        #pragma unroll
        for (int sp = 0; sp < 2; ++sp) {
            f32x4* accp = sp ? acc1 : acc0;
            #pragma unroll
            for (int n = 0; n < 8; ++n)
                #pragma unroll
                for (int r = 0; r < 4; ++r)
                    Kp[(sp * 16 + quad * 4 + r) * 136 + n * 16 + l15] =
                        (__bf16)accp[n][r];
        }
    }

    // ---- v: project, scatter into V^T ----
    proj32(A0, A1, wph + 2 * 16384, lane, acc0, acc1);
    {
        const int jbase = w * 32;
        #pragma unroll
        for (int sp = 0; sp < 2; ++sp) {
            f32x4* accp = sp ? acc1 : acc0;
            #pragma unroll
            for (int n = 0; n < 8; ++n)
                #pragma unroll
                for (int r = 0; r < 4; ++r)
                    VT[(n * 16 + l15) * 264 + jbase + sp * 16 + quad * 4 + r] =
                        (__bf16)accp[n][r];
        }
    }
    __syncthreads();

    // ---- attention: 4 heads, own 32 q-rows, sweep all 256 j ----
    uint2 ovh[4][2][2], ovl[4][2][2];
    #pragma unroll
    for (int h = 0; h < 4; ++h) {
        f32x4 O[2][2];
        float ls[2] = {0.f, 0.f};
        #pragma unroll
        for (int s = 0; s < 2; ++s) {
            O[s][0] = (f32x4){0.f, 0.f, 0.f, 0.f};
            O[s][1] = (f32x4){0.f, 0.f, 0.f, 0.f};
        }
        #pragma unroll 1
        for (int jb = 0; jb < NRES; jb += 32) {
            bf16x8 Kh[2];
            #pragma unroll
            for (int js = 0; js < 2; ++js)
                Kh[js] = *(const bf16x8*)&Kl[(jb + js * 16 + l15) * 136 +
                                             h * 32 + quad * 8];
            bf16x8 Vh2[2];
            #pragma unroll
            for (int c = 0; c < 2; ++c)
                Vh2[c] = *(const bf16x8*)&VT[(h * 32 + c * 16 + l15) * 264 +
                                             jb + quad * 8];
            #pragma unroll
            for (int s = 0; s < 2; ++s) {
                #pragma unroll
                for (int js = 0; js < 2; ++js) {
                    f32x4 S = (f32x4){0.f, 0.f, 0.f, 0.f};
                    S = mfma16(Kh[js], Qh[h][s], S);
                    size_t f4 = (size_t)h * 16384 + (size_t)(w * 2 + s) * 1024 +
                                (size_t)((jb >> 4) + js) * 64 + quad * 16 + l15;
                    float4 nb4 = *(const float4*)&nbP[f4 * 4];
                    float4 mb4 = *(const float4*)&biasrow[jb + js * 16 + quad * 4];
                    float p0 = __expf(S[0] + nb4.x + mb4.x - 4.0f);
                    float p1 = __expf(S[1] + nb4.y + mb4.y - 4.0f);
                    float p2 = __expf(S[2] + nb4.z + mb4.z - 4.0f);
                    float p3 = __expf(S[3] + nb4.w + mb4.w - 4.0f);
                    ls[s] += (p0 + p1) + (p2 + p3);
                    PK4 hh;
                    hh.b[0] = (__bf16)p0; hh.b[1] = (__bf16)p1;
                    hh.b[2] = (__bf16)p2; hh.b[3] = (__bf16)p3;
                    *(uint2*)&ph[l15 * 40 + js * 16 + quad * 4] = hh.u2;
                }
                bf16x8 Ph = *(const bf16x8*)&ph[l15 * 40 + quad * 8];
                #pragma unroll
                for (int c = 0; c < 2; ++c)
                    O[s][c] = mfma16(Vh2[c], Ph, O[s][c]);
            }
        }
        #pragma unroll
        for (int s = 0; s < 2; ++s) {
            ls[s] += __shfl_xor(ls[s], 16, 64);
            ls[s] += __shfl_xor(ls[s], 32, 64);
        }
        // gate + normalize + hi/lo pack (regs only)
        #pragma unroll
        for (int s = 0; s < 2; ++s) {
            float inv = 1.0f / ls[s];
            #pragma unroll
            for (int c = 0; c < 2; ++c) {
                const __half* gh = (const __half*)&greg[h][s][c];
                PK4 hh, lo;
                #pragma unroll
                for (int r = 0; r < 4; ++r) {
                    float v = O[s][c][r] * inv * (float)gh[r];
                    __bf16 hb; __bf16 lb; hilo(v, hb, lb);
                    hh.b[r] = hb; lo.b[r] = lb;
                }
                ovh[h][s][c] = hh.u2;
                ovl[h][s][c] = lo.u2;
            }
        }
    }
    __syncthreads();   // K/VT/p dead for all waves

    // ---- out GEMM: restage hi/lo through own plane, 3-term split MFMA ----
    {
        __bf16* const sth = aH;
        #pragma unroll
        for (int h = 0; h < 4; ++h)
            #pragma unroll
            for (int s = 0; s < 2; ++s)
                #pragma unroll
                for (int c = 0; c < 2; ++c)
                    *(uint2*)&sth[(s * 16 + l15) * 136 + h * 32 + c * 16 + quad * 4] =
                        ovh[h][s][c];
        bf16x8 Ah0[4], Ah1[4];
        #pragma unroll
        for (int kf = 0; kf < 4; ++kf) {
            Ah0[kf] = *(const bf16x8*)&sth[l15 * 136 + kf * 32 + quad * 8];
            Ah1[kf] = *(const bf16x8*)&sth[(16 + l15) * 136 + kf * 32 + quad * 8];
        }
        #pragma unroll
        for (int h = 0; h < 4; ++h)
            #pragma unroll
            for (int s = 0; s < 2; ++s)
                #pragma unroll
                for (int c = 0; c < 2; ++c)
                    *(uint2*)&sth[(s * 16 + l15) * 136 + h * 32 + c * 16 + quad * 4] =
                        ovl[h][s][c];
        bf16x8 Al0[4], Al1[4];
        #pragma unroll
        for (int kf = 0; kf < 4; ++kf) {
            Al0[kf] = *(const bf16x8*)&sth[l15 * 136 + kf * 32 + quad * 8];
            Al1[kf] = *(const bf16x8*)&sth[(16 + l15) * 136 + kf * 32 + quad * 8];
        }

        const __bf16* __restrict__ Bh = wph + (size_t)4 * 16384;
        const __bf16* __restrict__ Bl = wpl + (size_t)4 * 16384;
        #pragma unroll
        for (int n = 0; n < 8; ++n) {
            acc0[n] = (f32x4){0.f, 0.f, 0.f, 0.f};
            acc1[n] = (f32x4){0.f, 0.f, 0.f, 0.f};
        }
        #pragma unroll
        for (int kf = 0; kf < 4; ++kf)
            #pragma unroll
            for (int n = 0; n < 8; ++n) {
                size_t boff = (size_t)((n * 4 + kf) * 64 + lane) * 8;
                bf16x8 bh = *(const bf16x8*)&Bh[boff];
                bf16x8 bl = *(const bf16x8*)&Bl[boff];
                acc0[n] = mfma16(Ah0[kf], bh, acc0[n]);
                acc0[n] = mfma16(Ah0[kf], bl, acc0[n]);
                acc0[n] = mfma16(Al0[kf], bh, acc0[n]);
                acc1[n] = mfma16(Ah1[kf], bh, acc1[n]);
                acc1[n] = mfma16(Ah1[kf], bl, acc1[n]);
                acc1[n] = mfma16(Al1[kf], bh, acc1[n]);
            }

        const size_t rbase = (size_t)m * NRES + w * 32;
        #pragma unroll
        for (int n = 0; n < 8; ++n) {
            float b = bo[n * 16 + l15];
            #pragma unroll
            for (int r = 0; r < 4; ++r) {
                out[(rbase + quad * 4 + r) * CCH + n * 16 + l15] = acc0[n][r] + b;
                out[(rbase + 16 + quad * 4 + r) * CCH + n * 16 + l15] = acc1[n][r] + b;
            }
        }
    }
}

extern "C" void kernel_launch(void* const* d_in, const int* in_sizes, int n_in,
                              void* d_out, int out_size, void* d_ws, size_t ws_size,
                              hipStream_t stream)
{
    const float* act  = (const float*)d_in[0];
    const float* mask = (const float*)d_in[1];
    const float* ln_g = (const float*)d_in[2];
    const float* ln_b = (const float*)d_in[3];
    const float* wq   = (const float*)d_in[4];
    const float* wk   = (const float*)d_in[5];
    const float* wv   = (const float*)d_in[6];
    const float* w2d  = (const float*)d_in[7];
    const float* wg   = (const float*)d_in[8];
    const float* bg   = (const float*)d_in[9];
    const float* wo   = (const float*)d_in[10];
    const float* bo   = (const float*)d_in[11];
    float* out = (float*)d_out;

    float* nbP = (float*)d_ws;                 // 4*NROWS floats = 1 MB
    __bf16* wph = (__bf16*)(nbP + 4 * NROWS);  // 5*16384 bf16
    __bf16* wpl = wph + 5 * 16384;

    prep_kernel<<<40, 256, 0, stream>>>(wq, wk, wv, wg, wo, wph, wpl);
    nb_kernel<<<512, 256, 0, stream>>>(act, ln_g, ln_b, w2d, nbP);
    mega_kernel<<<256, 512, 0, stream>>>(
        act, ln_g, ln_b, wph, wpl, bg, mask, nbP, bo, out);
}